// Round 12
// baseline (204.473 us; speedup 1.0000x reference)
//
#include <hip/hip_runtime.h>

#define BB 16
#define NNODE 207
#define TTS 12
#define NE 1863
#define NEP2 1920 // NE padded to 30*64
#define NH 8
#define FD 768
#define HFD 6144
#define MM 3312   // BB*NNODE
#define MP 3328   // padded to 26*128

typedef short bf16x8 __attribute__((ext_vector_type(8)));
typedef float f32x4 __attribute__((ext_vector_type(4)));

typedef __attribute__((address_space(3))) unsigned int lds_u32;
typedef __attribute__((address_space(1))) const unsigned int glb_u32;

__device__ __forceinline__ unsigned short f2b(float f) {
    unsigned int u = __float_as_uint(f);
    u = (u + 0x7FFFu + ((u >> 16) & 1u)) >> 16;
    return (unsigned short)u;
}
__device__ __forceinline__ float b2f(unsigned short b) {
    return __uint_as_float(((unsigned int)b) << 16);
}

// ---------------- merged prep: wlr precompute | W transpose | CSR build --------
#define CSR_EBLK 468
__global__ __launch_bounds__(256) void prep_misc(const float* __restrict__ W1,
                                                 const float* __restrict__ al1, const float* __restrict__ ar1,
                                                 const float* __restrict__ W2,
                                                 const float* __restrict__ al2, const float* __restrict__ ar2,
                                                 float* __restrict__ wlr,
                                                 unsigned short* __restrict__ Wt1,
                                                 unsigned short* __restrict__ Wt2,
                                                 const int* __restrict__ dst,
                                                 int* __restrict__ ptr, int* __restrict__ cidx) {
    __shared__ __align__(16) char smem[16640];
    const int bid = blockIdx.x;
    const int t = threadIdx.x;
    const int wv = t >> 6, lane = t & 63;
    if (bid < 3072) {
        const int wid = bid * 4 + wv;   // 0..12287
        const int which = wid / 6144;
        const int r = wid % 6144;
        const int k = r >> 3, hh = r & 7;
        const float* W = which ? W2 : W1;
        const float* al = which ? al2 : al1;
        const float* ar = which ? ar2 : ar1;
        const float4* wp = (const float4*)(W + (size_t)k * HFD + hh * FD);
        const float4* ap = (const float4*)(al + hh * FD);
        const float4* rp = (const float4*)(ar + hh * FD);
        float sl = 0.f, sr = 0.f;
#pragma unroll
        for (int jj = 0; jj < 3; jj++) {
            int j = lane + jj * 64;
            float4 w = wp[j], a = ap[j], b = rp[j];
            sl += w.x * a.x + w.y * a.y + w.z * a.z + w.w * a.w;
            sr += w.x * b.x + w.y * b.y + w.z * b.z + w.w * b.w;
        }
#pragma unroll
        for (int off = 32; off > 0; off >>= 1) {
            sl += __shfl_down(sl, off);
            sr += __shfl_down(sr, off);
        }
        if (lane == 0) {
            wlr[(size_t)which * 12288 + 0 + hh * FD + k] = sl;
            wlr[(size_t)which * 12288 + 6144 + hh * FD + k] = sr;
        }
    } else if (bid < 5376) {
        float (*tile)[65] = (float(*)[65])smem;
        const int idx = bid - 3072;             // 0..2303
        const int which = idx / 1152;
        const int r2 = idx % 1152;
        const int k0 = (r2 % 12) * 64;
        const int n0 = (r2 / 12) * 64;
        const float* W = which ? W2 : W1;
        unsigned short* Wt = which ? Wt2 : Wt1;
        const int c = t & 63, r0 = t >> 6;
#pragma unroll
        for (int i = 0; i < 16; i++) {
            int r = r0 + i * 4;
            tile[r][c] = W[(size_t)(k0 + r) * HFD + n0 + c];
        }
        __syncthreads();
#pragma unroll
        for (int i = 0; i < 16; i++) {
            int r = r0 + i * 4;
            Wt[(size_t)(n0 + r) * FD + k0 + c] = f2b(tile[c][r]);
        }
    } else {
        int* dl = (int*)smem;
        const int b2 = bid - 5376;              // 0..519
        for (int i = t; i < NEP2; i += 256) dl[i] = (i < NE) ? dst[i] : 0x0FFFFFFF;
        __syncthreads();
        if (b2 < CSR_EBLK) {
            const int e = b2 * 4 + wv;
            if (e >= NE) return;
            const int d = dl[e];
            int pos = 0;
#pragma unroll
            for (int j = 0; j < 30; j++) {
                int i = lane + j * 64;
                int di = dl[i];
                pos += (int)(di < d) + (int)((i < e) & (di == d));
            }
#pragma unroll
            for (int off = 32; off > 0; off >>= 1) pos += __shfl_down(pos, off);
            if (lane == 0) cidx[pos] = e;
        } else {
            const int n = (b2 - CSR_EBLK) * 4 + wv;  // 0..207
            if (n > NNODE) return;
            int cnt = 0;
#pragma unroll
            for (int j = 0; j < 30; j++) cnt += (int)(dl[lane + j * 64] < n);
#pragma unroll
            for (int off = 32; off > 0; off >>= 1) cnt += __shfl_down(cnt, off);
            if (lane == 0) ptr[n] = cnt;  // ptr[NNODE] = NE
        }
    }
}

// ---------------- 1x1 convs -> h0, hbf; fused layer-1 el/er; esrc gather -------
__global__ __launch_bounds__(256) void prep_h(const float* __restrict__ x,
                                              const float* __restrict__ Ws, const float* __restrict__ bs,
                                              const float* __restrict__ Wc, const float* __restrict__ bc,
                                              const float* __restrict__ wl, const float* __restrict__ wr,
                                              const int* __restrict__ src, const int* __restrict__ cidx,
                                              int* __restrict__ esrc,
                                              float* __restrict__ h0, unsigned short* __restrict__ hbf,
                                              float* __restrict__ el, float* __restrict__ er) {
    __shared__ float redl[4][8], redr[4][8];
    const int bn = blockIdx.x;
    const int t = threadIdx.x;
    if (bn >= MP) {                     // esrc blocks (cidx written by prep_misc)
        int p = (bn - MP) * 256 + t;
        if (p < NE) esrc[p] = src[cidx[p]];
        return;
    }
    if (bn >= MM) {
#pragma unroll
        for (int c = 0; c < 3; c++) hbf[(size_t)bn * FD + c * 256 + t] = 0;
        return;
    }
    const int b = bn / NNODE, n = bn % NNODE;
    float pl[8] = {}, pr[8] = {};
#pragma unroll
    for (int c = 0; c < 3; c++) {
        int idx = c * 256 + t;          // 0..767
        int e = idx / TTS, tt = idx % TTS;
        float x0 = x[((size_t)(b * 2 + 0) * NNODE + n) * TTS + tt];
        float x1 = x[((size_t)(b * 2 + 1) * NNODE + n) * TTS + tt];
        float s1 = Ws[e * 2] * x0 + Ws[e * 2 + 1] * x1 + bs[e];
        float s2 = Wc[e * 2] * x0 + Wc[e * 2 + 1] * x1 + bc[e];
        s2 = s2 > 0.f ? s2 : 0.01f * s2;
        float v = s1 + s2;
        h0[(size_t)bn * FD + idx] = v;
        hbf[(size_t)bn * FD + idx] = f2b(v);
#pragma unroll
        for (int hh = 0; hh < 8; hh++) {
            pl[hh] += v * wl[hh * FD + idx];
            pr[hh] += v * wr[hh * FD + idx];
        }
    }
    const int wv = t >> 6, lane = t & 63;
#pragma unroll
    for (int hh = 0; hh < 8; hh++) {
        float a = pl[hh], c2 = pr[hh];
#pragma unroll
        for (int off = 32; off > 0; off >>= 1) {
            a += __shfl_down(a, off);
            c2 += __shfl_down(c2, off);
        }
        if (lane == 0) { redl[wv][hh] = a; redr[wv][hh] = c2; }
    }
    __syncthreads();
    if (t < 8) {
        el[bn * NH + t] = redl[0][t] + redl[1][t] + redl[2][t] + redl[3][t];
        er[bn * NH + t] = redr[0][t] + redr[1][t] + redr[2][t] + redr[3][t];
    }
}

// ---------------- MFMA GEMM: BK=32 double-buffer, counted vmcnt (T4) -----------
// C = A[MP][FD] @ Bt[HFD][FD]^T. Swizzle = r4/r5-verified 2-bit XOR (0 conflict):
// write = linear LDS dest + inverse-swizzled global source; read slot ^ rsw.
// Pipeline: STAGE next -> s_waitcnt vmcnt(4) -> s_barrier -> ds_read+MFMA ->
// s_barrier. vmcnt never drained to 0 in the loop (next tile stays in flight).
__global__ __launch_bounds__(256) void gemm_bf16(const unsigned short* __restrict__ A,
                                                 const unsigned short* __restrict__ Bt,
                                                 unsigned short* __restrict__ C) {
    __shared__ __align__(16) unsigned short Alds[2][128 * 32];
    __shared__ __align__(16) unsigned short Blds[2][128 * 32];
    const int t = threadIdx.x;
    const int lane = t & 63;
    const int wv = t >> 6;
    const int wr = (wv >> 1) * 64, wc = (wv & 1) * 64;
    const int mt = blockIdx.y * 128, nt = blockIdx.x * 128;
    const int lm = lane & 15;
    const int rsw = (lm >> 1) & 3;                 // read-side XOR
    const int s4 = lane >> 4;                      // k-slot 0..3
    const int rdoff = (s4 ^ rsw) * 8;

    const int r0 = (wv * 2) * 16 + (lane >> 2);
    const int r1 = (wv * 2 + 1) * 16 + (lane >> 2);
    const int cseg = (((lane & 3) ^ ((lane >> 3) & 3)) * 8);
    const unsigned short* ap0 = A + (size_t)(mt + r0) * FD + cseg;
    const unsigned short* ap1 = A + (size_t)(mt + r1) * FD + cseg;
    const unsigned short* bp0 = Bt + (size_t)(nt + r0) * FD + cseg;
    const unsigned short* bp1 = Bt + (size_t)(nt + r1) * FD + cseg;
    const int ldo0 = (wv * 2) * 512;
    const int ldo1 = (wv * 2 + 1) * 512;

    f32x4 acc[4][4] = {};
    // prologue: stage k-tile 0 into buffer 0
    __builtin_amdgcn_global_load_lds((glb_u32*)(ap0), (lds_u32*)(Alds[0] + ldo0), 16, 0, 0);
    __builtin_amdgcn_global_load_lds((glb_u32*)(ap1), (lds_u32*)(Alds[0] + ldo1), 16, 0, 0);
    __builtin_amdgcn_global_load_lds((glb_u32*)(bp0), (lds_u32*)(Blds[0] + ldo0), 16, 0, 0);
    __builtin_amdgcn_global_load_lds((glb_u32*)(bp1), (lds_u32*)(Blds[0] + ldo1), 16, 0, 0);

    int cur = 0;
#pragma unroll 1
    for (int ks = 0; ks < FD; ks += 32) {
        // stage NEXT tile into alternate buffer (last iter: harmless re-stage of
        // the same tile into the dead buffer — never read)
        const int kn = (ks + 32 < FD) ? ks + 32 : ks;
        __builtin_amdgcn_global_load_lds((glb_u32*)(ap0 + kn), (lds_u32*)(Alds[cur ^ 1] + ldo0), 16, 0, 0);
        __builtin_amdgcn_global_load_lds((glb_u32*)(ap1 + kn), (lds_u32*)(Alds[cur ^ 1] + ldo1), 16, 0, 0);
        __builtin_amdgcn_global_load_lds((glb_u32*)(bp0 + kn), (lds_u32*)(Blds[cur ^ 1] + ldo0), 16, 0, 0);
        __builtin_amdgcn_global_load_lds((glb_u32*)(bp1 + kn), (lds_u32*)(Blds[cur ^ 1] + ldo1), 16, 0, 0);
        // own buf[cur] loads landed (4 newer stay in flight), then block-wide sync
        asm volatile("s_waitcnt vmcnt(4)" ::: "memory");
        __builtin_amdgcn_s_barrier();
        asm volatile("" ::: "memory");   // fence: no LDS read hoists above barrier
        bf16x8 af[4], bfv[4];
#pragma unroll
        for (int i = 0; i < 4; i++)
            af[i] = *(const bf16x8*)(Alds[cur] + (wr + i * 16 + lm) * 32 + rdoff);
#pragma unroll
        for (int j = 0; j < 4; j++)
            bfv[j] = *(const bf16x8*)(Blds[cur] + (wc + j * 16 + lm) * 32 + rdoff);
#pragma unroll
        for (int i = 0; i < 4; i++)
#pragma unroll
            for (int j = 0; j < 4; j++)
                acc[i][j] = __builtin_amdgcn_mfma_f32_16x16x32_bf16(af[i], bfv[j], acc[i][j], 0, 0, 0);
        __builtin_amdgcn_s_barrier();    // reads consumed (MFMA issued) before
        cur ^= 1;                        // anyone re-stages this buffer
    }
    const int rbase = s4 * 4;
#pragma unroll
    for (int i = 0; i < 4; i++) {
#pragma unroll
        for (int r = 0; r < 4; r++) {
            int grow = mt + wr + i * 16 + rbase + r;
            if (grow < MM) {
#pragma unroll
                for (int j = 0; j < 4; j++) {
                    int gcol = nt + wc + j * 16 + lm;
                    C[(size_t)grow * HFD + gcol] = f2b(acc[i][j][r]);
                }
            }
        }
    }
}

// ---------------- message passing (256 thr, pipelined) + softmax + elu + mean --
template <int LAST>
__global__ __launch_bounds__(256) void msg_agg(const unsigned short* __restrict__ feat,
                                               const int* __restrict__ cptr, const int* __restrict__ esrc,
                                               const float* __restrict__ bias,
                                               const float* __restrict__ el_in, const float* __restrict__ er_in,
                                               unsigned short* __restrict__ hbf_out,
                                               const float* __restrict__ wl, const float* __restrict__ wr,
                                               float* __restrict__ el_out, float* __restrict__ er_out,
                                               const float* __restrict__ h0, float* __restrict__ out) {
    __shared__ float rstl[HFD];         // 24 KB
    __shared__ int src_l[32];
    __shared__ float alph[32][NH];
    __shared__ float redl[4][8], redr[4][8];
    __shared__ float sm_m[8], sm_i[8], sm_er[8];
    const int bn = (blockIdx.x & 7) * (MM / 8) + (blockIdx.x >> 3);
    const int b = bn / NNODE, n = bn % NNODE;
    const int t = threadIdx.x;
    const int p0 = cptr[n], p1 = cptr[n + 1];
    const int deg = p1 - p0;
    if (t < 64) {   // wave 0: online softmax stats per head
        const int h = t & 7, js = t >> 3;
        const float erv = er_in[(b * NNODE + n) * NH + h];
        float m = -1e30f, d = 0.f;
        for (int jb = 0; jb < deg; jb += 8) {
            int j = jb + js;
            float s = -1e30f, add = 0.f;
            if (j < deg) {
                int sn = esrc[p0 + j];
                s = el_in[(b * NNODE + sn) * NH + h] + erv;
                s = s > 0.f ? s : 0.2f * s;
                add = 1.f;
            }
            float mn = fmaxf(m, s);
            d = d * __expf(m - mn) + add * __expf(s - mn);
            m = mn;
        }
#pragma unroll
        for (int o = 8; o < 64; o <<= 1) {
            float mo = __shfl_xor(m, o), dd = __shfl_xor(d, o);
            float mn = fmaxf(m, mo);
            d = d * __expf(m - mn) + dd * __expf(mo - mn);
            m = mn;
        }
        if (js == 0) { sm_m[h] = m; sm_i[h] = 1.f / d; sm_er[h] = erv; }
    }
    __syncthreads();

    const int h0i = t / 96, h1i = (256 + t) / 96, h2i = (512 + t) / 96;
    float acc[3][8] = {};
    for (int base = p0; base < p1; base += 32) {
        const int cnt = min(32, p1 - base);
        if (t < cnt) src_l[t] = esrc[base + t];
        {
            int j = t >> 3, hh = t & 7;
            if (j < cnt) {
                float s = el_in[(b * NNODE + esrc[base + j]) * NH + hh] + sm_er[hh];
                s = s > 0.f ? s : 0.2f * s;
                alph[j][hh] = __expf(s - sm_m[hh]) * sm_i[hh];
            }
        }
        __syncthreads();
        // software-pipelined gather: prefetch row j2+1 while processing j2
        const unsigned short* fp = feat + (size_t)(b * NNODE + src_l[0]) * HFD;
        uint4 c0 = *(const uint4*)(fp + (size_t)(0 * 256 + t) * 8);
        uint4 c1 = *(const uint4*)(fp + (size_t)(1 * 256 + t) * 8);
        uint4 c2 = *(const uint4*)(fp + (size_t)(2 * 256 + t) * 8);
        for (int j2 = 0; j2 < cnt; j2++) {
            uint4 n0, n1, n2;
            if (j2 + 1 < cnt) {
                const unsigned short* np = feat + (size_t)(b * NNODE + src_l[j2 + 1]) * HFD;
                n0 = *(const uint4*)(np + (size_t)(0 * 256 + t) * 8);
                n1 = *(const uint4*)(np + (size_t)(1 * 256 + t) * 8);
                n2 = *(const uint4*)(np + (size_t)(2 * 256 + t) * 8);
            }
            const float a0 = alph[j2][h0i], a1 = alph[j2][h1i], a2 = alph[j2][h2i];
            unsigned int w;
            w = c0.x; acc[0][0] += a0 * b2f((unsigned short)w); acc[0][1] += a0 * b2f((unsigned short)(w >> 16));
            w = c0.y; acc[0][2] += a0 * b2f((unsigned short)w); acc[0][3] += a0 * b2f((unsigned short)(w >> 16));
            w = c0.z; acc[0][4] += a0 * b2f((unsigned short)w); acc[0][5] += a0 * b2f((unsigned short)(w >> 16));
            w = c0.w; acc[0][6] += a0 * b2f((unsigned short)w); acc[0][7] += a0 * b2f((unsigned short)(w >> 16));
            w = c1.x; acc[1][0] += a1 * b2f((unsigned short)w); acc[1][1] += a1 * b2f((unsigned short)(w >> 16));
            w = c1.y; acc[1][2] += a1 * b2f((unsigned short)w); acc[1][3] += a1 * b2f((unsigned short)(w >> 16));
            w = c1.z; acc[1][4] += a1 * b2f((unsigned short)w); acc[1][5] += a1 * b2f((unsigned short)(w >> 16));
            w = c1.w; acc[1][6] += a1 * b2f((unsigned short)w); acc[1][7] += a1 * b2f((unsigned short)(w >> 16));
            w = c2.x; acc[2][0] += a2 * b2f((unsigned short)w); acc[2][1] += a2 * b2f((unsigned short)(w >> 16));
            w = c2.y; acc[2][2] += a2 * b2f((unsigned short)w); acc[2][3] += a2 * b2f((unsigned short)(w >> 16));
            w = c2.z; acc[2][4] += a2 * b2f((unsigned short)w); acc[2][5] += a2 * b2f((unsigned short)(w >> 16));
            w = c2.w; acc[2][6] += a2 * b2f((unsigned short)w); acc[2][7] += a2 * b2f((unsigned short)(w >> 16));
            c0 = n0; c1 = n1; c2 = n2;
        }
        __syncthreads();
    }
#pragma unroll
    for (int c = 0; c < 3; c++) {
        int v = c * 256 + t;
#pragma unroll
        for (int u = 0; u < 8; u++) rstl[v * 8 + u] = acc[c][u];
    }
    __syncthreads();
    float pl[8] = {}, pr[8] = {};
#pragma unroll
    for (int q = 0; q < 3; q++) {
        int f = q * 256 + t;
        float val = 0.f;
#pragma unroll
        for (int hh = 0; hh < 8; hh++) {
            float r = rstl[hh * FD + f] + bias[hh * FD + f];
            val += (r > 0.f) ? r : (expf(r) - 1.f);
        }
        val *= 0.125f;
        if (LAST) {
            int e_ = f / TTS, tt_ = f % TTS;
            out[((size_t)(b * 64 + e_) * NNODE + n) * TTS + tt_] = h0[(size_t)bn * FD + f] + val;
        } else {
            hbf_out[(size_t)bn * FD + f] = f2b(val);
#pragma unroll
            for (int hh = 0; hh < 8; hh++) {
                pl[hh] += val * wl[hh * FD + f];
                pr[hh] += val * wr[hh * FD + f];
            }
        }
    }
    if (!LAST) {
        const int wv = t >> 6, lane = t & 63;
#pragma unroll
        for (int hh = 0; hh < 8; hh++) {
            float a = pl[hh], c2 = pr[hh];
#pragma unroll
            for (int off = 32; off > 0; off >>= 1) {
                a += __shfl_down(a, off);
                c2 += __shfl_down(c2, off);
            }
            if (lane == 0) { redl[wv][hh] = a; redr[wv][hh] = c2; }
        }
        __syncthreads();
        if (t < 8) {
            el_out[bn * NH + t] = redl[0][t] + redl[1][t] + redl[2][t] + redl[3][t];
            er_out[bn * NH + t] = redr[0][t] + redr[1][t] + redr[2][t] + redr[3][t];
        }
    }
}

extern "C" void kernel_launch(void* const* d_in, const int* in_sizes, int n_in,
                              void* d_out, int out_size, void* d_ws, size_t ws_size,
                              hipStream_t stream) {
    const float* x = (const float*)d_in[0];
    const int* src = (const int*)d_in[1];
    const int* dst = (const int*)d_in[2];
    const float* Ws = (const float*)d_in[3];
    const float* bs = (const float*)d_in[4];
    const float* Wc = (const float*)d_in[5];
    const float* bc = (const float*)d_in[6];
    const float* W1 = (const float*)d_in[7];
    const float* al1 = (const float*)d_in[8];
    const float* ar1 = (const float*)d_in[9];
    const float* b1 = (const float*)d_in[10];
    const float* W2 = (const float*)d_in[11];
    const float* al2 = (const float*)d_in[12];
    const float* ar2 = (const float*)d_in[13];
    const float* b2 = (const float*)d_in[14];
    float* out = (float*)d_out;

    char* w = (char*)d_ws;
    size_t off = 0;
    auto alloc = [&](size_t bytes) -> void* {
        void* p = w + off;
        off = (off + bytes + 255) & ~(size_t)255;
        return p;
    };
    float* h0 = (float*)alloc((size_t)MM * FD * 4);
    unsigned short* hbf = (unsigned short*)alloc((size_t)MP * FD * 2);
    unsigned short* Wt1 = (unsigned short*)alloc((size_t)HFD * FD * 2);
    unsigned short* Wt2 = (unsigned short*)alloc((size_t)HFD * FD * 2);
    unsigned short* feat = (unsigned short*)alloc((size_t)MM * HFD * 2);
    float* el = (float*)alloc((size_t)MM * NH * 4);
    float* er = (float*)alloc((size_t)MM * NH * 4);
    float* el2 = (float*)alloc((size_t)MM * NH * 4);
    float* er2 = (float*)alloc((size_t)MM * NH * 4);
    int* cptr = (int*)alloc((NNODE + 1) * 4);
    int* cidx = (int*)alloc(NE * 4);
    int* esrc = (int*)alloc(NE * 4);
    float* wlr = (float*)alloc((size_t)4 * 6144 * 4);  // wl1,wr1,wl2,wr2
    float* wl1 = wlr, * wr1 = wlr + 6144, * wl2 = wlr + 12288, * wr2 = wlr + 18432;

    // prep
    prep_misc<<<5896, 256, 0, stream>>>(W1, al1, ar1, W2, al2, ar2, wlr, Wt1, Wt2, dst, cptr, cidx);
    prep_h<<<MP + 8, 256, 0, stream>>>(x, Ws, bs, Wc, bc, wl1, wr1, src, cidx, esrc, h0, hbf, el, er);

    // layer 1
    gemm_bf16<<<dim3(48, 26), 256, 0, stream>>>(hbf, Wt1, feat);
    msg_agg<0><<<MM, 256, 0, stream>>>(feat, cptr, esrc, b1, el, er, hbf, wl2, wr2, el2, er2, nullptr, nullptr);

    // layer 2
    gemm_bf16<<<dim3(48, 26), 256, 0, stream>>>(hbf, Wt2, feat);
    msg_agg<1><<<MM, 256, 0, stream>>>(feat, cptr, esrc, b2, el2, er2, nullptr, nullptr, nullptr, nullptr, nullptr, h0, out);
}

// Round 13
// 198.444 us; speedup vs baseline: 1.0304x; 1.0304x over previous
//
#include <hip/hip_runtime.h>

#define BB 16
#define NNODE 207
#define TTS 12
#define NE 1863
#define NEP2 1920 // NE padded to 30*64
#define NH 8
#define FD 768
#define HFD 6144
#define MM 3312   // BB*NNODE
#define MP 3328   // padded to 26*128

typedef short bf16x8 __attribute__((ext_vector_type(8)));
typedef float f32x4 __attribute__((ext_vector_type(4)));

typedef __attribute__((address_space(3))) unsigned int lds_u32;
typedef __attribute__((address_space(1))) const unsigned int glb_u32;

__device__ __forceinline__ unsigned short f2b(float f) {
    unsigned int u = __float_as_uint(f);
    u = (u + 0x7FFFu + ((u >> 16) & 1u)) >> 16;
    return (unsigned short)u;
}
__device__ __forceinline__ float b2f(unsigned short b) {
    return __uint_as_float(((unsigned int)b) << 16);
}

// ---------------- prep 1: wlr precompute | CSR build (no dependencies) ---------
#define CSR_EBLK 468
__global__ __launch_bounds__(256) void prep_wc(const float* __restrict__ W1,
                                               const float* __restrict__ al1, const float* __restrict__ ar1,
                                               const float* __restrict__ W2,
                                               const float* __restrict__ al2, const float* __restrict__ ar2,
                                               float* __restrict__ wlr,
                                               const int* __restrict__ dst,
                                               int* __restrict__ ptr, int* __restrict__ cidx) {
    __shared__ int dl[NEP2];
    const int bid = blockIdx.x;
    const int t = threadIdx.x;
    const int wv = t >> 6, lane = t & 63;
    if (bid < 3072) {
        // wl[hh][k] = sum_f W[k][hh*768+f]*al[hh][f]; layout [which][l/r][8][768]
        const int wid = bid * 4 + wv;   // 0..12287
        const int which = wid / 6144;
        const int r = wid % 6144;
        const int k = r >> 3, hh = r & 7;
        const float* W = which ? W2 : W1;
        const float* al = which ? al2 : al1;
        const float* ar = which ? ar2 : ar1;
        const float4* wp = (const float4*)(W + (size_t)k * HFD + hh * FD);
        const float4* ap = (const float4*)(al + hh * FD);
        const float4* rp = (const float4*)(ar + hh * FD);
        float sl = 0.f, sr = 0.f;
#pragma unroll
        for (int jj = 0; jj < 3; jj++) {
            int j = lane + jj * 64;
            float4 w = wp[j], a = ap[j], b = rp[j];
            sl += w.x * a.x + w.y * a.y + w.z * a.z + w.w * a.w;
            sr += w.x * b.x + w.y * b.y + w.z * b.z + w.w * b.w;
        }
#pragma unroll
        for (int off = 32; off > 0; off >>= 1) {
            sl += __shfl_down(sl, off);
            sr += __shfl_down(sr, off);
        }
        if (lane == 0) {
            wlr[(size_t)which * 12288 + 0 + hh * FD + k] = sl;
            wlr[(size_t)which * 12288 + 6144 + hh * FD + k] = sr;
        }
    } else {
        // CSR: pos(e) = #{dst<d} + #{e'<e, dst==d}; ptr[n] = #{dst<n}
        const int b2 = bid - 3072;              // 0..519
        for (int i = t; i < NEP2; i += 256) dl[i] = (i < NE) ? dst[i] : 0x0FFFFFFF;
        __syncthreads();
        if (b2 < CSR_EBLK) {
            const int e = b2 * 4 + wv;
            if (e >= NE) return;
            const int d = dl[e];
            int pos = 0;
#pragma unroll
            for (int j = 0; j < 30; j++) {
                int i = lane + j * 64;
                int di = dl[i];
                pos += (int)(di < d) + (int)((i < e) & (di == d));
            }
#pragma unroll
            for (int off = 32; off > 0; off >>= 1) pos += __shfl_down(pos, off);
            if (lane == 0) cidx[pos] = e;
        } else {
            const int n = (b2 - CSR_EBLK) * 4 + wv;  // 0..207
            if (n > NNODE) return;
            int cnt = 0;
#pragma unroll
            for (int j = 0; j < 30; j++) cnt += (int)(dl[lane + j * 64] < n);
#pragma unroll
            for (int off = 32; off > 0; off >>= 1) cnt += __shfl_down(cnt, off);
            if (lane == 0) ptr[n] = cnt;  // ptr[NNODE] = NE
        }
    }
}

// ---------------- prep 2: conv+el/er | pad | esrc | W transpose ----------------
// bid<MM conv; MM..MP pad; MP..MP+8 esrc (cidx from prep_wc); >=MP+8 transpose.
__global__ __launch_bounds__(256) void prep_h(const float* __restrict__ x,
                                              const float* __restrict__ Ws, const float* __restrict__ bs,
                                              const float* __restrict__ Wc, const float* __restrict__ bc,
                                              const float* __restrict__ wl, const float* __restrict__ wr,
                                              const int* __restrict__ src, const int* __restrict__ cidx,
                                              int* __restrict__ esrc,
                                              float* __restrict__ h0, unsigned short* __restrict__ hbf,
                                              float* __restrict__ el, float* __restrict__ er,
                                              const float* __restrict__ W1, const float* __restrict__ W2,
                                              unsigned short* __restrict__ Wt1, unsigned short* __restrict__ Wt2) {
    __shared__ float tile[64][65];
    __shared__ float redl[4][8], redr[4][8];
    const int bn = blockIdx.x;
    const int t = threadIdx.x;
    if (bn >= MP + 8) {                 // ---- transpose: W[k][n] f32 -> Wt[n][k] bf16
        const int idx = bn - (MP + 8);  // 0..2303
        const int which = idx / 1152;
        const int r2 = idx % 1152;
        const int k0 = (r2 % 12) * 64;
        const int n0 = (r2 / 12) * 64;
        const float* W = which ? W2 : W1;
        unsigned short* Wt = which ? Wt2 : Wt1;
        const int c = t & 63, r0 = t >> 6;
#pragma unroll
        for (int i = 0; i < 16; i++) {
            int r = r0 + i * 4;
            tile[r][c] = W[(size_t)(k0 + r) * HFD + n0 + c];
        }
        __syncthreads();
#pragma unroll
        for (int i = 0; i < 16; i++) {
            int r = r0 + i * 4;
            Wt[(size_t)(n0 + r) * FD + k0 + c] = f2b(tile[c][r]);
        }
        return;
    }
    if (bn >= MP) {                     // ---- esrc gather
        int p = (bn - MP) * 256 + t;
        if (p < NE) esrc[p] = src[cidx[p]];
        return;
    }
    if (bn >= MM) {                     // ---- pad rows
#pragma unroll
        for (int c = 0; c < 3; c++) hbf[(size_t)bn * FD + c * 256 + t] = 0;
        return;
    }
    const int b = bn / NNODE, n = bn % NNODE;
    float pl[8] = {}, pr[8] = {};
#pragma unroll
    for (int c = 0; c < 3; c++) {
        int idx = c * 256 + t;          // 0..767
        int e = idx / TTS, tt = idx % TTS;
        float x0 = x[((size_t)(b * 2 + 0) * NNODE + n) * TTS + tt];
        float x1 = x[((size_t)(b * 2 + 1) * NNODE + n) * TTS + tt];
        float s1 = Ws[e * 2] * x0 + Ws[e * 2 + 1] * x1 + bs[e];
        float s2 = Wc[e * 2] * x0 + Wc[e * 2 + 1] * x1 + bc[e];
        s2 = s2 > 0.f ? s2 : 0.01f * s2;
        float v = s1 + s2;
        h0[(size_t)bn * FD + idx] = v;
        hbf[(size_t)bn * FD + idx] = f2b(v);
#pragma unroll
        for (int hh = 0; hh < 8; hh++) {
            pl[hh] += v * wl[hh * FD + idx];
            pr[hh] += v * wr[hh * FD + idx];
        }
    }
    const int wv = t >> 6, lane = t & 63;
#pragma unroll
    for (int hh = 0; hh < 8; hh++) {
        float a = pl[hh], c2 = pr[hh];
#pragma unroll
        for (int off = 32; off > 0; off >>= 1) {
            a += __shfl_down(a, off);
            c2 += __shfl_down(c2, off);
        }
        if (lane == 0) { redl[wv][hh] = a; redr[wv][hh] = c2; }
    }
    __syncthreads();
    if (t < 8) {
        el[bn * NH + t] = redl[0][t] + redl[1][t] + redl[2][t] + redl[3][t];
        er[bn * NH + t] = redr[0][t] + redr[1][t] + redr[2][t] + redr[3][t];
    }
}

// ---------------- MFMA GEMM, BK=64 single-buffer, 3-bit XOR swizzle (r8) -------
__global__ __launch_bounds__(256) void gemm_bf16(const unsigned short* __restrict__ A,
                                                 const unsigned short* __restrict__ Bt,
                                                 unsigned short* __restrict__ C) {
    __shared__ __align__(16) unsigned short Alds[128 * 64];  // 16 KB
    __shared__ __align__(16) unsigned short Blds[128 * 64];  // 16 KB
    const int t = threadIdx.x;
    const int lane = t & 63;
    const int wv = t >> 6;
    const int wr = (wv >> 1) * 64, wc = (wv & 1) * 64;
    const int mt = blockIdx.y * 128, nt = blockIdx.x * 128;
    const int lm = lane & 15;
    const int s4 = lane >> 4;                       // 0..3
    const int sl0 = ((0 + s4) ^ (lm & 7)) * 8;      // k-half 0 read slot (elems)
    const int sl1 = ((4 + s4) ^ (lm & 7)) * 8;      // k-half 1

    const int rr = lane >> 3;                       // 0..7
    const int ssl = ((lane & 7) ^ rr) * 8;          // global src slot offset (elems)
    const unsigned short* ap[4];
    const unsigned short* bp[4];
#pragma unroll
    for (int q = 0; q < 4; q++) {
        int row = wv * 32 + q * 8 + rr;
        ap[q] = A + (size_t)(mt + row) * FD + ssl;
        bp[q] = Bt + (size_t)(nt + row) * FD + ssl;
    }

    f32x4 acc[4][4] = {};
    for (int ks = 0; ks < FD; ks += 64) {
#pragma unroll
        for (int q = 0; q < 4; q++) {
            __builtin_amdgcn_global_load_lds((glb_u32*)(ap[q] + ks),
                (lds_u32*)(Alds + (wv * 4 + q) * 512), 16, 0, 0);
            __builtin_amdgcn_global_load_lds((glb_u32*)(bp[q] + ks),
                (lds_u32*)(Blds + (wv * 4 + q) * 512), 16, 0, 0);
        }
        __syncthreads();
        {
            bf16x8 af[4], bfv[4];
#pragma unroll
            for (int i = 0; i < 4; i++)
                af[i] = *(const bf16x8*)(Alds + (wr + i * 16 + lm) * 64 + sl0);
#pragma unroll
            for (int j = 0; j < 4; j++)
                bfv[j] = *(const bf16x8*)(Blds + (wc + j * 16 + lm) * 64 + sl0);
#pragma unroll
            for (int i = 0; i < 4; i++)
#pragma unroll
                for (int j = 0; j < 4; j++)
                    acc[i][j] = __builtin_amdgcn_mfma_f32_16x16x32_bf16(af[i], bfv[j], acc[i][j], 0, 0, 0);
        }
        {
            bf16x8 af[4], bfv[4];
#pragma unroll
            for (int i = 0; i < 4; i++)
                af[i] = *(const bf16x8*)(Alds + (wr + i * 16 + lm) * 64 + sl1);
#pragma unroll
            for (int j = 0; j < 4; j++)
                bfv[j] = *(const bf16x8*)(Blds + (wc + j * 16 + lm) * 64 + sl1);
#pragma unroll
            for (int i = 0; i < 4; i++)
#pragma unroll
                for (int j = 0; j < 4; j++)
                    acc[i][j] = __builtin_amdgcn_mfma_f32_16x16x32_bf16(af[i], bfv[j], acc[i][j], 0, 0, 0);
        }
        __syncthreads();
    }
    const int rbase = s4 * 4;
#pragma unroll
    for (int i = 0; i < 4; i++) {
#pragma unroll
        for (int r = 0; r < 4; r++) {
            int grow = mt + wr + i * 16 + rbase + r;
            if (grow < MM) {
#pragma unroll
                for (int j = 0; j < 4; j++) {
                    int gcol = nt + wc + j * 16 + lm;
                    C[(size_t)grow * HFD + gcol] = f2b(acc[i][j][r]);
                }
            }
        }
    }
}

// ---------------- message passing (256 thr, pipelined) + softmax + elu + mean --
template <int LAST>
__global__ __launch_bounds__(256) void msg_agg(const unsigned short* __restrict__ feat,
                                               const int* __restrict__ cptr, const int* __restrict__ esrc,
                                               const float* __restrict__ bias,
                                               const float* __restrict__ el_in, const float* __restrict__ er_in,
                                               unsigned short* __restrict__ hbf_out,
                                               const float* __restrict__ wl, const float* __restrict__ wr,
                                               float* __restrict__ el_out, float* __restrict__ er_out,
                                               const float* __restrict__ h0, float* __restrict__ out) {
    __shared__ float rstl[HFD];         // 24 KB
    __shared__ int src_l[32];
    __shared__ float alph[32][NH];
    __shared__ float redl[4][8], redr[4][8];
    __shared__ float sm_m[8], sm_i[8], sm_er[8];
    const int bn = (blockIdx.x & 7) * (MM / 8) + (blockIdx.x >> 3);
    const int b = bn / NNODE, n = bn % NNODE;
    const int t = threadIdx.x;
    const int p0 = cptr[n], p1 = cptr[n + 1];
    const int deg = p1 - p0;
    if (t < 64) {   // wave 0: online softmax stats per head
        const int h = t & 7, js = t >> 3;
        const float erv = er_in[(b * NNODE + n) * NH + h];
        float m = -1e30f, d = 0.f;
        for (int jb = 0; jb < deg; jb += 8) {
            int j = jb + js;
            float s = -1e30f, add = 0.f;
            if (j < deg) {
                int sn = esrc[p0 + j];
                s = el_in[(b * NNODE + sn) * NH + h] + erv;
                s = s > 0.f ? s : 0.2f * s;
                add = 1.f;
            }
            float mn = fmaxf(m, s);
            d = d * __expf(m - mn) + add * __expf(s - mn);
            m = mn;
        }
#pragma unroll
        for (int o = 8; o < 64; o <<= 1) {
            float mo = __shfl_xor(m, o), dd = __shfl_xor(d, o);
            float mn = fmaxf(m, mo);
            d = d * __expf(m - mn) + dd * __expf(mo - mn);
            m = mn;
        }
        if (js == 0) { sm_m[h] = m; sm_i[h] = 1.f / d; sm_er[h] = erv; }
    }
    __syncthreads();

    const int h0i = t / 96, h1i = (256 + t) / 96, h2i = (512 + t) / 96;
    float acc[3][8] = {};
    for (int base = p0; base < p1; base += 32) {
        const int cnt = min(32, p1 - base);
        if (t < cnt) src_l[t] = esrc[base + t];
        {
            int j = t >> 3, hh = t & 7;
            if (j < cnt) {
                float s = el_in[(b * NNODE + esrc[base + j]) * NH + hh] + sm_er[hh];
                s = s > 0.f ? s : 0.2f * s;
                alph[j][hh] = __expf(s - sm_m[hh]) * sm_i[hh];
            }
        }
        __syncthreads();
        // software-pipelined gather: prefetch row j2+1 while processing j2
        const unsigned short* fp = feat + (size_t)(b * NNODE + src_l[0]) * HFD;
        uint4 c0 = *(const uint4*)(fp + (size_t)(0 * 256 + t) * 8);
        uint4 c1 = *(const uint4*)(fp + (size_t)(1 * 256 + t) * 8);
        uint4 c2 = *(const uint4*)(fp + (size_t)(2 * 256 + t) * 8);
        for (int j2 = 0; j2 < cnt; j2++) {
            uint4 n0, n1, n2;
            if (j2 + 1 < cnt) {
                const unsigned short* np = feat + (size_t)(b * NNODE + src_l[j2 + 1]) * HFD;
                n0 = *(const uint4*)(np + (size_t)(0 * 256 + t) * 8);
                n1 = *(const uint4*)(np + (size_t)(1 * 256 + t) * 8);
                n2 = *(const uint4*)(np + (size_t)(2 * 256 + t) * 8);
            }
            const float a0 = alph[j2][h0i], a1 = alph[j2][h1i], a2 = alph[j2][h2i];
            unsigned int w;
            w = c0.x; acc[0][0] += a0 * b2f((unsigned short)w); acc[0][1] += a0 * b2f((unsigned short)(w >> 16));
            w = c0.y; acc[0][2] += a0 * b2f((unsigned short)w); acc[0][3] += a0 * b2f((unsigned short)(w >> 16));
            w = c0.z; acc[0][4] += a0 * b2f((unsigned short)w); acc[0][5] += a0 * b2f((unsigned short)(w >> 16));
            w = c0.w; acc[0][6] += a0 * b2f((unsigned short)w); acc[0][7] += a0 * b2f((unsigned short)(w >> 16));
            w = c1.x; acc[1][0] += a1 * b2f((unsigned short)w); acc[1][1] += a1 * b2f((unsigned short)(w >> 16));
            w = c1.y; acc[1][2] += a1 * b2f((unsigned short)w); acc[1][3] += a1 * b2f((unsigned short)(w >> 16));
            w = c1.z; acc[1][4] += a1 * b2f((unsigned short)w); acc[1][5] += a1 * b2f((unsigned short)(w >> 16));
            w = c1.w; acc[1][6] += a1 * b2f((unsigned short)w); acc[1][7] += a1 * b2f((unsigned short)(w >> 16));
            w = c2.x; acc[2][0] += a2 * b2f((unsigned short)w); acc[2][1] += a2 * b2f((unsigned short)(w >> 16));
            w = c2.y; acc[2][2] += a2 * b2f((unsigned short)w); acc[2][3] += a2 * b2f((unsigned short)(w >> 16));
            w = c2.z; acc[2][4] += a2 * b2f((unsigned short)w); acc[2][5] += a2 * b2f((unsigned short)(w >> 16));
            w = c2.w; acc[2][6] += a2 * b2f((unsigned short)w); acc[2][7] += a2 * b2f((unsigned short)(w >> 16));
            c0 = n0; c1 = n1; c2 = n2;
        }
        __syncthreads();
    }
#pragma unroll
    for (int c = 0; c < 3; c++) {
        int v = c * 256 + t;
#pragma unroll
        for (int u = 0; u < 8; u++) rstl[v * 8 + u] = acc[c][u];
    }
    __syncthreads();
    float pl[8] = {}, pr[8] = {};
#pragma unroll
    for (int q = 0; q < 3; q++) {
        int f = q * 256 + t;
        float val = 0.f;
#pragma unroll
        for (int hh = 0; hh < 8; hh++) {
            float r = rstl[hh * FD + f] + bias[hh * FD + f];
            val += (r > 0.f) ? r : (expf(r) - 1.f);
        }
        val *= 0.125f;
        if (LAST) {
            int e_ = f / TTS, tt_ = f % TTS;
            out[((size_t)(b * 64 + e_) * NNODE + n) * TTS + tt_] = h0[(size_t)bn * FD + f] + val;
        } else {
            hbf_out[(size_t)bn * FD + f] = f2b(val);
#pragma unroll
            for (int hh = 0; hh < 8; hh++) {
                pl[hh] += val * wl[hh * FD + f];
                pr[hh] += val * wr[hh * FD + f];
            }
        }
    }
    if (!LAST) {
        const int wv = t >> 6, lane = t & 63;
#pragma unroll
        for (int hh = 0; hh < 8; hh++) {
            float a = pl[hh], c2 = pr[hh];
#pragma unroll
            for (int off = 32; off > 0; off >>= 1) {
                a += __shfl_down(a, off);
                c2 += __shfl_down(c2, off);
            }
            if (lane == 0) { redl[wv][hh] = a; redr[wv][hh] = c2; }
        }
        __syncthreads();
        if (t < 8) {
            el_out[bn * NH + t] = redl[0][t] + redl[1][t] + redl[2][t] + redl[3][t];
            er_out[bn * NH + t] = redr[0][t] + redr[1][t] + redr[2][t] + redr[3][t];
        }
    }
}

extern "C" void kernel_launch(void* const* d_in, const int* in_sizes, int n_in,
                              void* d_out, int out_size, void* d_ws, size_t ws_size,
                              hipStream_t stream) {
    const float* x = (const float*)d_in[0];
    const int* src = (const int*)d_in[1];
    const int* dst = (const int*)d_in[2];
    const float* Ws = (const float*)d_in[3];
    const float* bs = (const float*)d_in[4];
    const float* Wc = (const float*)d_in[5];
    const float* bc = (const float*)d_in[6];
    const float* W1 = (const float*)d_in[7];
    const float* al1 = (const float*)d_in[8];
    const float* ar1 = (const float*)d_in[9];
    const float* b1 = (const float*)d_in[10];
    const float* W2 = (const float*)d_in[11];
    const float* al2 = (const float*)d_in[12];
    const float* ar2 = (const float*)d_in[13];
    const float* b2 = (const float*)d_in[14];
    float* out = (float*)d_out;

    char* w = (char*)d_ws;
    size_t off = 0;
    auto alloc = [&](size_t bytes) -> void* {
        void* p = w + off;
        off = (off + bytes + 255) & ~(size_t)255;
        return p;
    };
    float* h0 = (float*)alloc((size_t)MM * FD * 4);
    unsigned short* hbf = (unsigned short*)alloc((size_t)MP * FD * 2);
    unsigned short* Wt1 = (unsigned short*)alloc((size_t)HFD * FD * 2);
    unsigned short* Wt2 = (unsigned short*)alloc((size_t)HFD * FD * 2);
    unsigned short* feat = (unsigned short*)alloc((size_t)MM * HFD * 2);
    float* el = (float*)alloc((size_t)MM * NH * 4);
    float* er = (float*)alloc((size_t)MM * NH * 4);
    float* el2 = (float*)alloc((size_t)MM * NH * 4);
    float* er2 = (float*)alloc((size_t)MM * NH * 4);
    int* cptr = (int*)alloc((NNODE + 1) * 4);
    int* cidx = (int*)alloc(NE * 4);
    int* esrc = (int*)alloc(NE * 4);
    float* wlr = (float*)alloc((size_t)4 * 6144 * 4);  // wl1,wr1,wl2,wr2
    float* wl1 = wlr, * wr1 = wlr + 6144, * wl2 = wlr + 12288, * wr2 = wlr + 18432;

    // prep: (wlr | csr) -> (conv | pad | esrc | transpose)
    prep_wc<<<3592, 256, 0, stream>>>(W1, al1, ar1, W2, al2, ar2, wlr, dst, cptr, cidx);
    prep_h<<<MP + 8 + 2304, 256, 0, stream>>>(x, Ws, bs, Wc, bc, wl1, wr1, src, cidx, esrc,
                                              h0, hbf, el, er, W1, W2, Wt1, Wt2);

    // layer 1
    gemm_bf16<<<dim3(48, 26), 256, 0, stream>>>(hbf, Wt1, feat);
    msg_agg<0><<<MM, 256, 0, stream>>>(feat, cptr, esrc, b1, el, er, hbf, wl2, wr2, el2, er2, nullptr, nullptr);

    // layer 2
    gemm_bf16<<<dim3(48, 26), 256, 0, stream>>>(hbf, Wt2, feat);
    msg_agg<1><<<MM, 256, 0, stream>>>(feat, cptr, esrc, b2, el2, er2, nullptr, nullptr, nullptr, nullptr, nullptr, h0, out);
}

// Round 14
// 193.203 us; speedup vs baseline: 1.0583x; 1.0271x over previous
//
#include <hip/hip_runtime.h>

#define BB 16
#define NNODE 207
#define TTS 12
#define NE 1863
#define NEP2 1920 // NE padded to 30*64
#define NH 8
#define FD 768
#define HFD 6144
#define MM 3312   // BB*NNODE
#define MP 3328   // padded to 26*128

typedef short bf16x8 __attribute__((ext_vector_type(8)));
typedef float f32x4 __attribute__((ext_vector_type(4)));

typedef __attribute__((address_space(3))) unsigned int lds_u32;
typedef __attribute__((address_space(1))) const unsigned int glb_u32;

__device__ __forceinline__ unsigned short f2b(float f) {
    unsigned int u = __float_as_uint(f);
    u = (u + 0x7FFFu + ((u >> 16) & 1u)) >> 16;
    return (unsigned short)u;
}
__device__ __forceinline__ float b2f(unsigned short b) {
    return __uint_as_float(((unsigned int)b) << 16);
}

// ---------------- prep 1: wlr precompute | CSR build (no dependencies) ---------
#define CSR_EBLK 468
__global__ __launch_bounds__(256) void prep_wc(const float* __restrict__ W1,
                                               const float* __restrict__ al1, const float* __restrict__ ar1,
                                               const float* __restrict__ W2,
                                               const float* __restrict__ al2, const float* __restrict__ ar2,
                                               float* __restrict__ wlr,
                                               const int* __restrict__ dst,
                                               int* __restrict__ ptr, int* __restrict__ cidx) {
    __shared__ int dl[NEP2];
    const int bid = blockIdx.x;
    const int t = threadIdx.x;
    const int wv = t >> 6, lane = t & 63;
    if (bid < 3072) {
        // wl[hh][k] = sum_f W[k][hh*768+f]*al[hh][f]; layout [which][l/r][8][768]
        const int wid = bid * 4 + wv;   // 0..12287
        const int which = wid / 6144;
        const int r = wid % 6144;
        const int k = r >> 3, hh = r & 7;
        const float* W = which ? W2 : W1;
        const float* al = which ? al2 : al1;
        const float* ar = which ? ar2 : ar1;
        const float4* wp = (const float4*)(W + (size_t)k * HFD + hh * FD);
        const float4* ap = (const float4*)(al + hh * FD);
        const float4* rp = (const float4*)(ar + hh * FD);
        float sl = 0.f, sr = 0.f;
#pragma unroll
        for (int jj = 0; jj < 3; jj++) {
            int j = lane + jj * 64;
            float4 w = wp[j], a = ap[j], b = rp[j];
            sl += w.x * a.x + w.y * a.y + w.z * a.z + w.w * a.w;
            sr += w.x * b.x + w.y * b.y + w.z * b.z + w.w * b.w;
        }
#pragma unroll
        for (int off = 32; off > 0; off >>= 1) {
            sl += __shfl_down(sl, off);
            sr += __shfl_down(sr, off);
        }
        if (lane == 0) {
            wlr[(size_t)which * 12288 + 0 + hh * FD + k] = sl;
            wlr[(size_t)which * 12288 + 6144 + hh * FD + k] = sr;
        }
    } else {
        // CSR: pos(e) = #{dst<d} + #{e'<e, dst==d}; ptr[n] = #{dst<n}
        const int b2 = bid - 3072;              // 0..519
        for (int i = t; i < NEP2; i += 256) dl[i] = (i < NE) ? dst[i] : 0x0FFFFFFF;
        __syncthreads();
        if (b2 < CSR_EBLK) {
            const int e = b2 * 4 + wv;
            if (e >= NE) return;
            const int d = dl[e];
            int pos = 0;
#pragma unroll
            for (int j = 0; j < 30; j++) {
                int i = lane + j * 64;
                int di = dl[i];
                pos += (int)(di < d) + (int)((i < e) & (di == d));
            }
#pragma unroll
            for (int off = 32; off > 0; off >>= 1) pos += __shfl_down(pos, off);
            if (lane == 0) cidx[pos] = e;
        } else {
            const int n = (b2 - CSR_EBLK) * 4 + wv;  // 0..207
            if (n > NNODE) return;
            int cnt = 0;
#pragma unroll
            for (int j = 0; j < 30; j++) cnt += (int)(dl[lane + j * 64] < n);
#pragma unroll
            for (int off = 32; off > 0; off >>= 1) cnt += __shfl_down(cnt, off);
            if (lane == 0) ptr[n] = cnt;  // ptr[NNODE] = NE
        }
    }
}

// ---------------- prep 2: conv+el/er | pad | esrc | W transpose ----------------
__global__ __launch_bounds__(256) void prep_h(const float* __restrict__ x,
                                              const float* __restrict__ Ws, const float* __restrict__ bs,
                                              const float* __restrict__ Wc, const float* __restrict__ bc,
                                              const float* __restrict__ wl, const float* __restrict__ wr,
                                              const int* __restrict__ src, const int* __restrict__ cidx,
                                              int* __restrict__ esrc,
                                              float* __restrict__ h0, unsigned short* __restrict__ hbf,
                                              float* __restrict__ el, float* __restrict__ er,
                                              const float* __restrict__ W1, const float* __restrict__ W2,
                                              unsigned short* __restrict__ Wt1, unsigned short* __restrict__ Wt2) {
    __shared__ float tile[64][65];
    __shared__ float redl[4][8], redr[4][8];
    const int bn = blockIdx.x;
    const int t = threadIdx.x;
    if (bn >= MP + 8) {                 // ---- transpose: W[k][n] f32 -> Wt[n][k] bf16
        const int idx = bn - (MP + 8);  // 0..2303
        const int which = idx / 1152;
        const int r2 = idx % 1152;
        const int k0 = (r2 % 12) * 64;
        const int n0 = (r2 / 12) * 64;
        const float* W = which ? W2 : W1;
        unsigned short* Wt = which ? Wt2 : Wt1;
        const int c = t & 63, r0 = t >> 6;
#pragma unroll
        for (int i = 0; i < 16; i++) {
            int r = r0 + i * 4;
            tile[r][c] = W[(size_t)(k0 + r) * HFD + n0 + c];
        }
        __syncthreads();
#pragma unroll
        for (int i = 0; i < 16; i++) {
            int r = r0 + i * 4;
            Wt[(size_t)(n0 + r) * FD + k0 + c] = f2b(tile[c][r]);
        }
        return;
    }
    if (bn >= MP) {                     // ---- esrc gather
        int p = (bn - MP) * 256 + t;
        if (p < NE) esrc[p] = src[cidx[p]];
        return;
    }
    if (bn >= MM) {                     // ---- pad rows
#pragma unroll
        for (int c = 0; c < 3; c++) hbf[(size_t)bn * FD + c * 256 + t] = 0;
        return;
    }
    const int b = bn / NNODE, n = bn % NNODE;
    float pl[8] = {}, pr[8] = {};
#pragma unroll
    for (int c = 0; c < 3; c++) {
        int idx = c * 256 + t;          // 0..767
        int e = idx / TTS, tt = idx % TTS;
        float x0 = x[((size_t)(b * 2 + 0) * NNODE + n) * TTS + tt];
        float x1 = x[((size_t)(b * 2 + 1) * NNODE + n) * TTS + tt];
        float s1 = Ws[e * 2] * x0 + Ws[e * 2 + 1] * x1 + bs[e];
        float s2 = Wc[e * 2] * x0 + Wc[e * 2 + 1] * x1 + bc[e];
        s2 = s2 > 0.f ? s2 : 0.01f * s2;
        float v = s1 + s2;
        h0[(size_t)bn * FD + idx] = v;
        hbf[(size_t)bn * FD + idx] = f2b(v);
#pragma unroll
        for (int hh = 0; hh < 8; hh++) {
            pl[hh] += v * wl[hh * FD + idx];
            pr[hh] += v * wr[hh * FD + idx];
        }
    }
    const int wv = t >> 6, lane = t & 63;
#pragma unroll
    for (int hh = 0; hh < 8; hh++) {
        float a = pl[hh], c2 = pr[hh];
#pragma unroll
        for (int off = 32; off > 0; off >>= 1) {
            a += __shfl_down(a, off);
            c2 += __shfl_down(c2, off);
        }
        if (lane == 0) { redl[wv][hh] = a; redr[wv][hh] = c2; }
    }
    __syncthreads();
    if (t < 8) {
        el[bn * NH + t] = redl[0][t] + redl[1][t] + redl[2][t] + redl[3][t];
        er[bn * NH + t] = redr[0][t] + redr[1][t] + redr[2][t] + redr[3][t];
    }
}

// ---------------- MFMA GEMM, BK=64 single-buffer, 3-bit XOR swizzle (r8) -------
__global__ __launch_bounds__(256) void gemm_bf16(const unsigned short* __restrict__ A,
                                                 const unsigned short* __restrict__ Bt,
                                                 unsigned short* __restrict__ C) {
    __shared__ __align__(16) unsigned short Alds[128 * 64];  // 16 KB
    __shared__ __align__(16) unsigned short Blds[128 * 64];  // 16 KB
    const int t = threadIdx.x;
    const int lane = t & 63;
    const int wv = t >> 6;
    const int wr = (wv >> 1) * 64, wc = (wv & 1) * 64;
    const int mt = blockIdx.y * 128, nt = blockIdx.x * 128;
    const int lm = lane & 15;
    const int s4 = lane >> 4;                       // 0..3
    const int sl0 = ((0 + s4) ^ (lm & 7)) * 8;      // k-half 0 read slot (elems)
    const int sl1 = ((4 + s4) ^ (lm & 7)) * 8;      // k-half 1

    const int rr = lane >> 3;                       // 0..7
    const int ssl = ((lane & 7) ^ rr) * 8;          // global src slot offset (elems)
    const unsigned short* ap[4];
    const unsigned short* bp[4];
#pragma unroll
    for (int q = 0; q < 4; q++) {
        int row = wv * 32 + q * 8 + rr;
        ap[q] = A + (size_t)(mt + row) * FD + ssl;
        bp[q] = Bt + (size_t)(nt + row) * FD + ssl;
    }

    f32x4 acc[4][4] = {};
    for (int ks = 0; ks < FD; ks += 64) {
#pragma unroll
        for (int q = 0; q < 4; q++) {
            __builtin_amdgcn_global_load_lds((glb_u32*)(ap[q] + ks),
                (lds_u32*)(Alds + (wv * 4 + q) * 512), 16, 0, 0);
            __builtin_amdgcn_global_load_lds((glb_u32*)(bp[q] + ks),
                (lds_u32*)(Blds + (wv * 4 + q) * 512), 16, 0, 0);
        }
        __syncthreads();
        {
            bf16x8 af[4], bfv[4];
#pragma unroll
            for (int i = 0; i < 4; i++)
                af[i] = *(const bf16x8*)(Alds + (wr + i * 16 + lm) * 64 + sl0);
#pragma unroll
            for (int j = 0; j < 4; j++)
                bfv[j] = *(const bf16x8*)(Blds + (wc + j * 16 + lm) * 64 + sl0);
#pragma unroll
            for (int i = 0; i < 4; i++)
#pragma unroll
                for (int j = 0; j < 4; j++)
                    acc[i][j] = __builtin_amdgcn_mfma_f32_16x16x32_bf16(af[i], bfv[j], acc[i][j], 0, 0, 0);
        }
        {
            bf16x8 af[4], bfv[4];
#pragma unroll
            for (int i = 0; i < 4; i++)
                af[i] = *(const bf16x8*)(Alds + (wr + i * 16 + lm) * 64 + sl1);
#pragma unroll
            for (int j = 0; j < 4; j++)
                bfv[j] = *(const bf16x8*)(Blds + (wc + j * 16 + lm) * 64 + sl1);
#pragma unroll
            for (int i = 0; i < 4; i++)
#pragma unroll
                for (int j = 0; j < 4; j++)
                    acc[i][j] = __builtin_amdgcn_mfma_f32_16x16x32_bf16(af[i], bfv[j], acc[i][j], 0, 0, 0);
        }
        __syncthreads();
    }
    const int rbase = s4 * 4;
#pragma unroll
    for (int i = 0; i < 4; i++) {
#pragma unroll
        for (int r = 0; r < 4; r++) {
            int grow = mt + wr + i * 16 + rbase + r;
            if (grow < MM) {
#pragma unroll
                for (int j = 0; j < 4; j++) {
                    int gcol = nt + wc + j * 16 + lm;
                    C[(size_t)grow * HFD + gcol] = f2b(acc[i][j][r]);
                }
            }
        }
    }
}

// ---------------- message passing: row-0 prefetch under softmax, __expf elu ----
template <int LAST>
__global__ __launch_bounds__(256) void msg_agg(const unsigned short* __restrict__ feat,
                                               const int* __restrict__ cptr, const int* __restrict__ esrc,
                                               const float* __restrict__ bias,
                                               const float* __restrict__ el_in, const float* __restrict__ er_in,
                                               unsigned short* __restrict__ hbf_out,
                                               const float* __restrict__ wl, const float* __restrict__ wr,
                                               float* __restrict__ el_out, float* __restrict__ er_out,
                                               const float* __restrict__ h0, float* __restrict__ out) {
    __shared__ float rstl[HFD];         // 24 KB
    __shared__ int src_l[32];
    __shared__ float alph[32][NH];
    __shared__ float redl[4][8], redr[4][8];
    __shared__ float sm_m[8], sm_i[8], sm_er[8];
    const int bn = (blockIdx.x & 7) * (MM / 8) + (blockIdx.x >> 3);
    const int b = bn / NNODE, n = bn % NNODE;
    const int t = threadIdx.x;
    const int p0 = cptr[n], p1 = cptr[n + 1];
    const int deg = p1 - p0;            // >= 1 (self loops guaranteed)

    // phase 0: stage first-chunk src indices, then ISSUE row-0 loads so the
    // ~500cy L2/L3 latency hides under the softmax pre-phase (T14 pattern)
    const int cnt0 = min(32, deg);
    if (t < cnt0) src_l[t] = esrc[p0 + t];
    __syncthreads();
    const unsigned short* fp0 = feat + (size_t)(b * NNODE + src_l[0]) * HFD;
    uint4 c0 = *(const uint4*)(fp0 + (size_t)(0 * 256 + t) * 8);
    uint4 c1 = *(const uint4*)(fp0 + (size_t)(1 * 256 + t) * 8);
    uint4 c2 = *(const uint4*)(fp0 + (size_t)(2 * 256 + t) * 8);

    if (t < 64) {   // wave 0: online softmax stats per head (loads in flight)
        const int h = t & 7, js = t >> 3;
        const float erv = er_in[(b * NNODE + n) * NH + h];
        float m = -1e30f, d = 0.f;
        for (int jb = 0; jb < deg; jb += 8) {
            int j = jb + js;
            float s = -1e30f, add = 0.f;
            if (j < deg) {
                int sn = esrc[p0 + j];
                s = el_in[(b * NNODE + sn) * NH + h] + erv;
                s = s > 0.f ? s : 0.2f * s;
                add = 1.f;
            }
            float mn = fmaxf(m, s);
            d = d * __expf(m - mn) + add * __expf(s - mn);
            m = mn;
        }
#pragma unroll
        for (int o = 8; o < 64; o <<= 1) {
            float mo = __shfl_xor(m, o), dd = __shfl_xor(d, o);
            float mn = fmaxf(m, mo);
            d = d * __expf(m - mn) + dd * __expf(mo - mn);
            m = mn;
        }
        if (js == 0) { sm_m[h] = m; sm_i[h] = 1.f / d; sm_er[h] = erv; }
    }
    __syncthreads();    // sm_* ready

    const int h0i = t / 96, h1i = (256 + t) / 96, h2i = (512 + t) / 96;
    float acc[3][8] = {};
    for (int base = p0; base < p1; base += 32) {
        const int cnt = min(32, (int)(p1 - base));
        if (base != p0) {
            __syncthreads();            // prior chunk's gather done with src_l/alph
            if (t < cnt) src_l[t] = esrc[base + t];
        }
        {
            int j = t >> 3, hh = t & 7;
            if (j < cnt) {
                float s = el_in[(b * NNODE + esrc[base + j]) * NH + hh] + sm_er[hh];
                s = s > 0.f ? s : 0.2f * s;
                alph[j][hh] = __expf(s - sm_m[hh]) * sm_i[hh];
            }
        }
        __syncthreads();                // src_l + alph visible
        if (base != p0) {               // later chunks: load row 0 now
            const unsigned short* fp = feat + (size_t)(b * NNODE + src_l[0]) * HFD;
            c0 = *(const uint4*)(fp + (size_t)(0 * 256 + t) * 8);
            c1 = *(const uint4*)(fp + (size_t)(1 * 256 + t) * 8);
            c2 = *(const uint4*)(fp + (size_t)(2 * 256 + t) * 8);
        }
        for (int j2 = 0; j2 < cnt; j2++) {
            uint4 n0, n1, n2;
            if (j2 + 1 < cnt) {
                const unsigned short* np = feat + (size_t)(b * NNODE + src_l[j2 + 1]) * HFD;
                n0 = *(const uint4*)(np + (size_t)(0 * 256 + t) * 8);
                n1 = *(const uint4*)(np + (size_t)(1 * 256 + t) * 8);
                n2 = *(const uint4*)(np + (size_t)(2 * 256 + t) * 8);
            }
            const float a0 = alph[j2][h0i], a1 = alph[j2][h1i], a2 = alph[j2][h2i];
            unsigned int w;
            w = c0.x; acc[0][0] += a0 * b2f((unsigned short)w); acc[0][1] += a0 * b2f((unsigned short)(w >> 16));
            w = c0.y; acc[0][2] += a0 * b2f((unsigned short)w); acc[0][3] += a0 * b2f((unsigned short)(w >> 16));
            w = c0.z; acc[0][4] += a0 * b2f((unsigned short)w); acc[0][5] += a0 * b2f((unsigned short)(w >> 16));
            w = c0.w; acc[0][6] += a0 * b2f((unsigned short)w); acc[0][7] += a0 * b2f((unsigned short)(w >> 16));
            w = c1.x; acc[1][0] += a1 * b2f((unsigned short)w); acc[1][1] += a1 * b2f((unsigned short)(w >> 16));
            w = c1.y; acc[1][2] += a1 * b2f((unsigned short)w); acc[1][3] += a1 * b2f((unsigned short)(w >> 16));
            w = c1.z; acc[1][4] += a1 * b2f((unsigned short)w); acc[1][5] += a1 * b2f((unsigned short)(w >> 16));
            w = c1.w; acc[1][6] += a1 * b2f((unsigned short)w); acc[1][7] += a1 * b2f((unsigned short)(w >> 16));
            w = c2.x; acc[2][0] += a2 * b2f((unsigned short)w); acc[2][1] += a2 * b2f((unsigned short)(w >> 16));
            w = c2.y; acc[2][2] += a2 * b2f((unsigned short)w); acc[2][3] += a2 * b2f((unsigned short)(w >> 16));
            w = c2.z; acc[2][4] += a2 * b2f((unsigned short)w); acc[2][5] += a2 * b2f((unsigned short)(w >> 16));
            w = c2.w; acc[2][6] += a2 * b2f((unsigned short)w); acc[2][7] += a2 * b2f((unsigned short)(w >> 16));
            c0 = n0; c1 = n1; c2 = n2;
        }
    }
    __syncthreads();                    // gather done (also guards rstl reuse)
#pragma unroll
    for (int c = 0; c < 3; c++) {
        int v = c * 256 + t;
#pragma unroll
        for (int u = 0; u < 8; u++) rstl[v * 8 + u] = acc[c][u];
    }
    __syncthreads();
    float pl[8] = {}, pr[8] = {};
#pragma unroll
    for (int q = 0; q < 3; q++) {
        int f = q * 256 + t;
        float val = 0.f;
#pragma unroll
        for (int hh = 0; hh < 8; hh++) {
            float r = rstl[hh * FD + f] + bias[hh * FD + f];
            val += (r > 0.f) ? r : (__expf(r) - 1.f);
        }
        val *= 0.125f;
        if (LAST) {
            int e_ = f / TTS, tt_ = f % TTS;
            out[((size_t)(b * 64 + e_) * NNODE + n) * TTS + tt_] = h0[(size_t)bn * FD + f] + val;
        } else {
            hbf_out[(size_t)bn * FD + f] = f2b(val);
#pragma unroll
            for (int hh = 0; hh < 8; hh++) {
                pl[hh] += val * wl[hh * FD + f];
                pr[hh] += val * wr[hh * FD + f];
            }
        }
    }
    if (!LAST) {
        const int wv = t >> 6, lane = t & 63;
#pragma unroll
        for (int hh = 0; hh < 8; hh++) {
            float a = pl[hh], c2 = pr[hh];
#pragma unroll
            for (int off = 32; off > 0; off >>= 1) {
                a += __shfl_down(a, off);
                c2 += __shfl_down(c2, off);
            }
            if (lane == 0) { redl[wv][hh] = a; redr[wv][hh] = c2; }
        }
        __syncthreads();
        if (t < 8) {
            el_out[bn * NH + t] = redl[0][t] + redl[1][t] + redl[2][t] + redl[3][t];
            er_out[bn * NH + t] = redr[0][t] + redr[1][t] + redr[2][t] + redr[3][t];
        }
    }
}

extern "C" void kernel_launch(void* const* d_in, const int* in_sizes, int n_in,
                              void* d_out, int out_size, void* d_ws, size_t ws_size,
                              hipStream_t stream) {
    const float* x = (const float*)d_in[0];
    const int* src = (const int*)d_in[1];
    const int* dst = (const int*)d_in[2];
    const float* Ws = (const float*)d_in[3];
    const float* bs = (const float*)d_in[4];
    const float* Wc = (const float*)d_in[5];
    const float* bc = (const float*)d_in[6];
    const float* W1 = (const float*)d_in[7];
    const float* al1 = (const float*)d_in[8];
    const float* ar1 = (const float*)d_in[9];
    const float* b1 = (const float*)d_in[10];
    const float* W2 = (const float*)d_in[11];
    const float* al2 = (const float*)d_in[12];
    const float* ar2 = (const float*)d_in[13];
    const float* b2 = (const float*)d_in[14];
    float* out = (float*)d_out;

    char* w = (char*)d_ws;
    size_t off = 0;
    auto alloc = [&](size_t bytes) -> void* {
        void* p = w + off;
        off = (off + bytes + 255) & ~(size_t)255;
        return p;
    };
    float* h0 = (float*)alloc((size_t)MM * FD * 4);
    unsigned short* hbf = (unsigned short*)alloc((size_t)MP * FD * 2);
    unsigned short* Wt1 = (unsigned short*)alloc((size_t)HFD * FD * 2);
    unsigned short* Wt2 = (unsigned short*)alloc((size_t)HFD * FD * 2);
    unsigned short* feat = (unsigned short*)alloc((size_t)MM * HFD * 2);
    float* el = (float*)alloc((size_t)MM * NH * 4);
    float* er = (float*)alloc((size_t)MM * NH * 4);
    float* el2 = (float*)alloc((size_t)MM * NH * 4);
    float* er2 = (float*)alloc((size_t)MM * NH * 4);
    int* cptr = (int*)alloc((NNODE + 1) * 4);
    int* cidx = (int*)alloc(NE * 4);
    int* esrc = (int*)alloc(NE * 4);
    float* wlr = (float*)alloc((size_t)4 * 6144 * 4);  // wl1,wr1,wl2,wr2
    float* wl1 = wlr, * wr1 = wlr + 6144, * wl2 = wlr + 12288, * wr2 = wlr + 18432;

    // prep: (wlr | csr) -> (conv | pad | esrc | transpose)
    prep_wc<<<3592, 256, 0, stream>>>(W1, al1, ar1, W2, al2, ar2, wlr, dst, cptr, cidx);
    prep_h<<<MP + 8 + 2304, 256, 0, stream>>>(x, Ws, bs, Wc, bc, wl1, wr1, src, cidx, esrc,
                                              h0, hbf, el, er, W1, W2, Wt1, Wt2);

    // layer 1
    gemm_bf16<<<dim3(48, 26), 256, 0, stream>>>(hbf, Wt1, feat);
    msg_agg<0><<<MM, 256, 0, stream>>>(feat, cptr, esrc, b1, el, er, hbf, wl2, wr2, el2, er2, nullptr, nullptr);

    // layer 2
    gemm_bf16<<<dim3(48, 26), 256, 0, stream>>>(hbf, Wt2, feat);
    msg_agg<1><<<MM, 256, 0, stream>>>(feat, cptr, esrc, b2, el2, er2, nullptr, nullptr, nullptr, nullptr, nullptr, h0, out);
}

// Round 15
// 191.919 us; speedup vs baseline: 1.0654x; 1.0067x over previous
//
#include <hip/hip_runtime.h>

#define BB 16
#define NNODE 207
#define TTS 12
#define NE 1863
#define NEP2 1920 // NE padded to 30*64
#define NH 8
#define FD 768
#define HFD 6144
#define MM 3312   // BB*NNODE
#define MP 3328   // padded to 26*128

typedef short bf16x8 __attribute__((ext_vector_type(8)));
typedef float f32x4 __attribute__((ext_vector_type(4)));

typedef __attribute__((address_space(3))) unsigned int lds_u32;
typedef __attribute__((address_space(1))) const unsigned int glb_u32;

__device__ __forceinline__ unsigned short f2b(float f) {
    unsigned int u = __float_as_uint(f);
    u = (u + 0x7FFFu + ((u >> 16) & 1u)) >> 16;
    return (unsigned short)u;
}
__device__ __forceinline__ float b2f(unsigned short b) {
    return __uint_as_float(((unsigned int)b) << 16);
}

// ---------------- prep 1: wlr precompute | CSR build (+esrc fused) -------------
#define CSR_EBLK 468
__global__ __launch_bounds__(256) void prep_wc(const float* __restrict__ W1,
                                               const float* __restrict__ al1, const float* __restrict__ ar1,
                                               const float* __restrict__ W2,
                                               const float* __restrict__ al2, const float* __restrict__ ar2,
                                               float* __restrict__ wlr,
                                               const int* __restrict__ dst, const int* __restrict__ src,
                                               int* __restrict__ ptr, int* __restrict__ cidx,
                                               int* __restrict__ esrc) {
    __shared__ int dl[NEP2];
    const int bid = blockIdx.x;
    const int t = threadIdx.x;
    const int wv = t >> 6, lane = t & 63;
    if (bid < 3072) {
        // wl[hh][k] = sum_f W[k][hh*768+f]*al[hh][f]; layout [which][l/r][8][768]
        const int wid = bid * 4 + wv;   // 0..12287
        const int which = wid / 6144;
        const int r = wid % 6144;
        const int k = r >> 3, hh = r & 7;
        const float* W = which ? W2 : W1;
        const float* al = which ? al2 : al1;
        const float* ar = which ? ar2 : ar1;
        const float4* wp = (const float4*)(W + (size_t)k * HFD + hh * FD);
        const float4* ap = (const float4*)(al + hh * FD);
        const float4* rp = (const float4*)(ar + hh * FD);
        float sl = 0.f, sr = 0.f;
#pragma unroll
        for (int jj = 0; jj < 3; jj++) {
            int j = lane + jj * 64;
            float4 w = wp[j], a = ap[j], b = rp[j];
            sl += w.x * a.x + w.y * a.y + w.z * a.z + w.w * a.w;
            sr += w.x * b.x + w.y * b.y + w.z * b.z + w.w * b.w;
        }
#pragma unroll
        for (int off = 32; off > 0; off >>= 1) {
            sl += __shfl_down(sl, off);
            sr += __shfl_down(sr, off);
        }
        if (lane == 0) {
            wlr[(size_t)which * 12288 + 0 + hh * FD + k] = sl;
            wlr[(size_t)which * 12288 + 6144 + hh * FD + k] = sr;
        }
    } else {
        // CSR: pos(e) = #{dst<d} + #{e'<e, dst==d}; ptr[n] = #{dst<n}
        const int b2 = bid - 3072;              // 0..519
        for (int i = t; i < NEP2; i += 256) dl[i] = (i < NE) ? dst[i] : 0x0FFFFFFF;
        __syncthreads();
        if (b2 < CSR_EBLK) {
            const int e = b2 * 4 + wv;
            if (e >= NE) return;
            const int d = dl[e];
            int pos = 0;
#pragma unroll
            for (int j = 0; j < 30; j++) {
                int i = lane + j * 64;
                int di = dl[i];
                pos += (int)(di < d) + (int)((i < e) & (di == d));
            }
#pragma unroll
            for (int off = 32; off > 0; off >>= 1) pos += __shfl_down(pos, off);
            if (lane == 0) { cidx[pos] = e; esrc[pos] = src[e]; }
        } else {
            const int n = (b2 - CSR_EBLK) * 4 + wv;  // 0..207
            if (n > NNODE) return;
            int cnt = 0;
#pragma unroll
            for (int j = 0; j < 30; j++) cnt += (int)(dl[lane + j * 64] < n);
#pragma unroll
            for (int off = 32; off > 0; off >>= 1) cnt += __shfl_down(cnt, off);
            if (lane == 0) ptr[n] = cnt;  // ptr[NNODE] = NE
        }
    }
}

// ---------------- prep 2: conv+el/er | pad | W transpose -----------------------
__global__ __launch_bounds__(256) void prep_h(const float* __restrict__ x,
                                              const float* __restrict__ Ws, const float* __restrict__ bs,
                                              const float* __restrict__ Wc, const float* __restrict__ bc,
                                              const float* __restrict__ wl, const float* __restrict__ wr,
                                              float* __restrict__ h0, unsigned short* __restrict__ hbf,
                                              float* __restrict__ el, float* __restrict__ er,
                                              const float* __restrict__ W1, const float* __restrict__ W2,
                                              unsigned short* __restrict__ Wt1, unsigned short* __restrict__ Wt2) {
    __shared__ float tile[64][65];
    __shared__ float redl[4][8], redr[4][8];
    const int bn = blockIdx.x;
    const int t = threadIdx.x;
    if (bn >= MP) {                     // ---- transpose: W[k][n] f32 -> Wt[n][k] bf16
        const int idx = bn - MP;        // 0..2303
        const int which = idx / 1152;
        const int r2 = idx % 1152;
        const int k0 = (r2 % 12) * 64;
        const int n0 = (r2 / 12) * 64;
        const float* W = which ? W2 : W1;
        unsigned short* Wt = which ? Wt2 : Wt1;
        const int c = t & 63, r0 = t >> 6;
#pragma unroll
        for (int i = 0; i < 16; i++) {
            int r = r0 + i * 4;
            tile[r][c] = W[(size_t)(k0 + r) * HFD + n0 + c];
        }
        __syncthreads();
#pragma unroll
        for (int i = 0; i < 16; i++) {
            int r = r0 + i * 4;
            Wt[(size_t)(n0 + r) * FD + k0 + c] = f2b(tile[c][r]);
        }
        return;
    }
    if (bn >= MM) {                     // ---- pad rows
#pragma unroll
        for (int c = 0; c < 3; c++) hbf[(size_t)bn * FD + c * 256 + t] = 0;
        return;
    }
    const int b = bn / NNODE, n = bn % NNODE;
    float pl[8] = {}, pr[8] = {};
#pragma unroll
    for (int c = 0; c < 3; c++) {
        int idx = c * 256 + t;          // 0..767
        int e = idx / TTS, tt = idx % TTS;
        float x0 = x[((size_t)(b * 2 + 0) * NNODE + n) * TTS + tt];
        float x1 = x[((size_t)(b * 2 + 1) * NNODE + n) * TTS + tt];
        float s1 = Ws[e * 2] * x0 + Ws[e * 2 + 1] * x1 + bs[e];
        float s2 = Wc[e * 2] * x0 + Wc[e * 2 + 1] * x1 + bc[e];
        s2 = s2 > 0.f ? s2 : 0.01f * s2;
        float v = s1 + s2;
        h0[(size_t)bn * FD + idx] = v;
        hbf[(size_t)bn * FD + idx] = f2b(v);
#pragma unroll
        for (int hh = 0; hh < 8; hh++) {
            pl[hh] += v * wl[hh * FD + idx];
            pr[hh] += v * wr[hh * FD + idx];
        }
    }
    const int wv = t >> 6, lane = t & 63;
#pragma unroll
    for (int hh = 0; hh < 8; hh++) {
        float a = pl[hh], c2 = pr[hh];
#pragma unroll
        for (int off = 32; off > 0; off >>= 1) {
            a += __shfl_down(a, off);
            c2 += __shfl_down(c2, off);
        }
        if (lane == 0) { redl[wv][hh] = a; redr[wv][hh] = c2; }
    }
    __syncthreads();
    if (t < 8) {
        el[bn * NH + t] = redl[0][t] + redl[1][t] + redl[2][t] + redl[3][t];
        er[bn * NH + t] = redr[0][t] + redr[1][t] + redr[2][t] + redr[3][t];
    }
}

// ---------------- MFMA GEMM, BK=64 single-buffer, 3-bit XOR swizzle (r8) -------
// feat is padded to MP rows -> no bounds check in the epilogue.
__global__ __launch_bounds__(256) void gemm_bf16(const unsigned short* __restrict__ A,
                                                 const unsigned short* __restrict__ Bt,
                                                 unsigned short* __restrict__ C) {
    __shared__ __align__(16) unsigned short Alds[128 * 64];  // 16 KB
    __shared__ __align__(16) unsigned short Blds[128 * 64];  // 16 KB
    const int t = threadIdx.x;
    const int lane = t & 63;
    const int wv = t >> 6;
    const int wr = (wv >> 1) * 64, wc = (wv & 1) * 64;
    const int mt = blockIdx.y * 128, nt = blockIdx.x * 128;
    const int lm = lane & 15;
    const int s4 = lane >> 4;                       // 0..3
    const int sl0 = ((0 + s4) ^ (lm & 7)) * 8;      // k-half 0 read slot (elems)
    const int sl1 = ((4 + s4) ^ (lm & 7)) * 8;      // k-half 1

    const int rr = lane >> 3;                       // 0..7
    const int ssl = ((lane & 7) ^ rr) * 8;          // global src slot offset (elems)
    const unsigned short* ap[4];
    const unsigned short* bp[4];
#pragma unroll
    for (int q = 0; q < 4; q++) {
        int row = wv * 32 + q * 8 + rr;
        ap[q] = A + (size_t)(mt + row) * FD + ssl;
        bp[q] = Bt + (size_t)(nt + row) * FD + ssl;
    }

    f32x4 acc[4][4] = {};
    for (int ks = 0; ks < FD; ks += 64) {
#pragma unroll
        for (int q = 0; q < 4; q++) {
            __builtin_amdgcn_global_load_lds((glb_u32*)(ap[q] + ks),
                (lds_u32*)(Alds + (wv * 4 + q) * 512), 16, 0, 0);
            __builtin_amdgcn_global_load_lds((glb_u32*)(bp[q] + ks),
                (lds_u32*)(Blds + (wv * 4 + q) * 512), 16, 0, 0);
        }
        __syncthreads();
        {
            bf16x8 af[4], bfv[4];
#pragma unroll
            for (int i = 0; i < 4; i++)
                af[i] = *(const bf16x8*)(Alds + (wr + i * 16 + lm) * 64 + sl0);
#pragma unroll
            for (int j = 0; j < 4; j++)
                bfv[j] = *(const bf16x8*)(Blds + (wc + j * 16 + lm) * 64 + sl0);
#pragma unroll
            for (int i = 0; i < 4; i++)
#pragma unroll
                for (int j = 0; j < 4; j++)
                    acc[i][j] = __builtin_amdgcn_mfma_f32_16x16x32_bf16(af[i], bfv[j], acc[i][j], 0, 0, 0);
        }
        {
            bf16x8 af[4], bfv[4];
#pragma unroll
            for (int i = 0; i < 4; i++)
                af[i] = *(const bf16x8*)(Alds + (wr + i * 16 + lm) * 64 + sl1);
#pragma unroll
            for (int j = 0; j < 4; j++)
                bfv[j] = *(const bf16x8*)(Blds + (wc + j * 16 + lm) * 64 + sl1);
#pragma unroll
            for (int i = 0; i < 4; i++)
#pragma unroll
                for (int j = 0; j < 4; j++)
                    acc[i][j] = __builtin_amdgcn_mfma_f32_16x16x32_bf16(af[i], bfv[j], acc[i][j], 0, 0, 0);
        }
        __syncthreads();
    }
    const int rbase = s4 * 4;
#pragma unroll
    for (int i = 0; i < 4; i++) {
#pragma unroll
        for (int r = 0; r < 4; r++) {
            int grow = mt + wr + i * 16 + rbase + r;
#pragma unroll
            for (int j = 0; j < 4; j++) {
                int gcol = nt + wc + j * 16 + lm;
                C[(size_t)grow * HFD + gcol] = f2b(acc[i][j][r]);
            }
        }
    }
}

// ---------------- message passing: cached edge scores, prefetch, __expf --------
template <int LAST>
__global__ __launch_bounds__(256) void msg_agg(const unsigned short* __restrict__ feat,
                                               const int* __restrict__ cptr, const int* __restrict__ esrc,
                                               const float* __restrict__ bias,
                                               const float* __restrict__ el_in, const float* __restrict__ er_in,
                                               unsigned short* __restrict__ hbf_out,
                                               const float* __restrict__ wl, const float* __restrict__ wr,
                                               float* __restrict__ el_out, float* __restrict__ er_out,
                                               const float* __restrict__ h0, float* __restrict__ out) {
    __shared__ float rstl[HFD];         // 24 KB
    __shared__ int src_l[32];
    __shared__ float alph[32][NH];
    __shared__ float redl[4][8], redr[4][8];
    __shared__ float sm_m[8], sm_i[8], sm_er[8];
    const int bn = (blockIdx.x & 7) * (MM / 8) + (blockIdx.x >> 3);
    const int b = bn / NNODE, n = bn % NNODE;
    const int t = threadIdx.x;
    const int p0 = cptr[n], p1 = cptr[n + 1];
    const int deg = p1 - p0;            // >= 1 (self loops guaranteed)

    // phase 0: stage first-chunk src indices, then ISSUE row-0 loads so the
    // L2/L3 latency hides under the softmax pre-phase (T14 pattern)
    const int cnt0 = min(32, deg);
    if (t < cnt0) src_l[t] = esrc[p0 + t];
    __syncthreads();
    const unsigned short* fp0 = feat + (size_t)(b * NNODE + src_l[0]) * HFD;
    uint4 c0 = *(const uint4*)(fp0 + (size_t)(0 * 256 + t) * 8);
    uint4 c1 = *(const uint4*)(fp0 + (size_t)(1 * 256 + t) * 8);
    uint4 c2 = *(const uint4*)(fp0 + (size_t)(2 * 256 + t) * 8);

    if (t < 64) {   // wave 0: online softmax stats per head (loads in flight);
                    // also caches leaky scores for the first chunk in alph[][]
        const int h = t & 7, js = t >> 3;
        const float erv = er_in[(b * NNODE + n) * NH + h];
        float m = -1e30f, d = 0.f;
        for (int jb = 0; jb < deg; jb += 8) {
            int j = jb + js;
            float s = -1e30f, add = 0.f;
            if (j < deg) {
                int sn = esrc[p0 + j];
                s = el_in[(b * NNODE + sn) * NH + h] + erv;
                s = s > 0.f ? s : 0.2f * s;
                add = 1.f;
                if (j < 32) alph[j][h] = s;
            }
            float mn = fmaxf(m, s);
            d = d * __expf(m - mn) + add * __expf(s - mn);
            m = mn;
        }
#pragma unroll
        for (int o = 8; o < 64; o <<= 1) {
            float mo = __shfl_xor(m, o), dd = __shfl_xor(d, o);
            float mn = fmaxf(m, mo);
            d = d * __expf(m - mn) + dd * __expf(mo - mn);
            m = mn;
        }
        if (js == 0) { sm_m[h] = m; sm_i[h] = 1.f / d; sm_er[h] = erv; }
    }
    __syncthreads();    // sm_* + cached scores ready

    const int h0i = t / 96, h1i = (256 + t) / 96, h2i = (512 + t) / 96;
    float acc[3][8] = {};
    for (int base = p0; base < p1; base += 32) {
        const int cnt = min(32, (int)(p1 - base));
        if (base != p0) {
            __syncthreads();            // prior chunk's gather done with src_l/alph
            if (t < cnt) src_l[t] = esrc[base + t];
        }
        {
            int j = t >> 3, hh = t & 7;
            if (j < cnt) {
                if (base == p0) {       // first chunk: scores cached in alph
                    alph[j][hh] = __expf(alph[j][hh] - sm_m[hh]) * sm_i[hh];
                } else {
                    float s = el_in[(b * NNODE + esrc[base + j]) * NH + hh] + sm_er[hh];
                    s = s > 0.f ? s : 0.2f * s;
                    alph[j][hh] = __expf(s - sm_m[hh]) * sm_i[hh];
                }
            }
        }
        __syncthreads();                // src_l + alph visible
        if (base != p0) {               // later chunks: load row 0 now
            const unsigned short* fp = feat + (size_t)(b * NNODE + src_l[0]) * HFD;
            c0 = *(const uint4*)(fp + (size_t)(0 * 256 + t) * 8);
            c1 = *(const uint4*)(fp + (size_t)(1 * 256 + t) * 8);
            c2 = *(const uint4*)(fp + (size_t)(2 * 256 + t) * 8);
        }
        for (int j2 = 0; j2 < cnt; j2++) {
            uint4 n0, n1, n2;
            if (j2 + 1 < cnt) {
                const unsigned short* np = feat + (size_t)(b * NNODE + src_l[j2 + 1]) * HFD;
                n0 = *(const uint4*)(np + (size_t)(0 * 256 + t) * 8);
                n1 = *(const uint4*)(np + (size_t)(1 * 256 + t) * 8);
                n2 = *(const uint4*)(np + (size_t)(2 * 256 + t) * 8);
            }
            const float a0 = alph[j2][h0i], a1 = alph[j2][h1i], a2 = alph[j2][h2i];
            unsigned int w;
            w = c0.x; acc[0][0] += a0 * b2f((unsigned short)w); acc[0][1] += a0 * b2f((unsigned short)(w >> 16));
            w = c0.y; acc[0][2] += a0 * b2f((unsigned short)w); acc[0][3] += a0 * b2f((unsigned short)(w >> 16));
            w = c0.z; acc[0][4] += a0 * b2f((unsigned short)w); acc[0][5] += a0 * b2f((unsigned short)(w >> 16));
            w = c0.w; acc[0][6] += a0 * b2f((unsigned short)w); acc[0][7] += a0 * b2f((unsigned short)(w >> 16));
            w = c1.x; acc[1][0] += a1 * b2f((unsigned short)w); acc[1][1] += a1 * b2f((unsigned short)(w >> 16));
            w = c1.y; acc[1][2] += a1 * b2f((unsigned short)w); acc[1][3] += a1 * b2f((unsigned short)(w >> 16));
            w = c1.z; acc[1][4] += a1 * b2f((unsigned short)w); acc[1][5] += a1 * b2f((unsigned short)(w >> 16));
            w = c1.w; acc[1][6] += a1 * b2f((unsigned short)w); acc[1][7] += a1 * b2f((unsigned short)(w >> 16));
            w = c2.x; acc[2][0] += a2 * b2f((unsigned short)w); acc[2][1] += a2 * b2f((unsigned short)(w >> 16));
            w = c2.y; acc[2][2] += a2 * b2f((unsigned short)w); acc[2][3] += a2 * b2f((unsigned short)(w >> 16));
            w = c2.z; acc[2][4] += a2 * b2f((unsigned short)w); acc[2][5] += a2 * b2f((unsigned short)(w >> 16));
            w = c2.w; acc[2][6] += a2 * b2f((unsigned short)w); acc[2][7] += a2 * b2f((unsigned short)(w >> 16));
            c0 = n0; c1 = n1; c2 = n2;
        }
    }
    __syncthreads();                    // gather done (also guards rstl reuse)
#pragma unroll
    for (int c = 0; c < 3; c++) {
        int v = c * 256 + t;
#pragma unroll
        for (int u = 0; u < 8; u++) rstl[v * 8 + u] = acc[c][u];
    }
    __syncthreads();
    float pl[8] = {}, pr[8] = {};
#pragma unroll
    for (int q = 0; q < 3; q++) {
        int f = q * 256 + t;
        float val = 0.f;
#pragma unroll
        for (int hh = 0; hh < 8; hh++) {
            float r = rstl[hh * FD + f] + bias[hh * FD + f];
            val += (r > 0.f) ? r : (__expf(r) - 1.f);
        }
        val *= 0.125f;
        if (LAST) {
            int e_ = f / TTS, tt_ = f % TTS;
            out[((size_t)(b * 64 + e_) * NNODE + n) * TTS + tt_] = h0[(size_t)bn * FD + f] + val;
        } else {
            hbf_out[(size_t)bn * FD + f] = f2b(val);
#pragma unroll
            for (int hh = 0; hh < 8; hh++) {
                pl[hh] += val * wl[hh * FD + f];
                pr[hh] += val * wr[hh * FD + f];
            }
        }
    }
    if (!LAST) {
        const int wv = t >> 6, lane = t & 63;
#pragma unroll
        for (int hh = 0; hh < 8; hh++) {
            float a = pl[hh], c2 = pr[hh];
#pragma unroll
            for (int off = 32; off > 0; off >>= 1) {
                a += __shfl_down(a, off);
                c2 += __shfl_down(c2, off);
            }
            if (lane == 0) { redl[wv][hh] = a; redr[wv][hh] = c2; }
        }
        __syncthreads();
        if (t < 8) {
            el_out[bn * NH + t] = redl[0][t] + redl[1][t] + redl[2][t] + redl[3][t];
            er_out[bn * NH + t] = redr[0][t] + redr[1][t] + redr[2][t] + redr[3][t];
        }
    }
}

extern "C" void kernel_launch(void* const* d_in, const int* in_sizes, int n_in,
                              void* d_out, int out_size, void* d_ws, size_t ws_size,
                              hipStream_t stream) {
    const float* x = (const float*)d_in[0];
    const int* src = (const int*)d_in[1];
    const int* dst = (const int*)d_in[2];
    const float* Ws = (const float*)d_in[3];
    const float* bs = (const float*)d_in[4];
    const float* Wc = (const float*)d_in[5];
    const float* bc = (const float*)d_in[6];
    const float* W1 = (const float*)d_in[7];
    const float* al1 = (const float*)d_in[8];
    const float* ar1 = (const float*)d_in[9];
    const float* b1 = (const float*)d_in[10];
    const float* W2 = (const float*)d_in[11];
    const float* al2 = (const float*)d_in[12];
    const float* ar2 = (const float*)d_in[13];
    const float* b2 = (const float*)d_in[14];
    float* out = (float*)d_out;

    char* w = (char*)d_ws;
    size_t off = 0;
    auto alloc = [&](size_t bytes) -> void* {
        void* p = w + off;
        off = (off + bytes + 255) & ~(size_t)255;
        return p;
    };
    float* h0 = (float*)alloc((size_t)MM * FD * 4);
    unsigned short* hbf = (unsigned short*)alloc((size_t)MP * FD * 2);
    unsigned short* Wt1 = (unsigned short*)alloc((size_t)HFD * FD * 2);
    unsigned short* Wt2 = (unsigned short*)alloc((size_t)HFD * FD * 2);
    unsigned short* feat = (unsigned short*)alloc((size_t)MP * HFD * 2);  // padded rows
    float* el = (float*)alloc((size_t)MM * NH * 4);
    float* er = (float*)alloc((size_t)MM * NH * 4);
    float* el2 = (float*)alloc((size_t)MM * NH * 4);
    float* er2 = (float*)alloc((size_t)MM * NH * 4);
    int* cptr = (int*)alloc((NNODE + 1) * 4);
    int* cidx = (int*)alloc(NE * 4);
    int* esrc = (int*)alloc(NE * 4);
    float* wlr = (float*)alloc((size_t)4 * 6144 * 4);  // wl1,wr1,wl2,wr2
    float* wl1 = wlr, * wr1 = wlr + 6144, * wl2 = wlr + 12288, * wr2 = wlr + 18432;

    // prep: (wlr | csr+esrc) -> (conv | pad | transpose)
    prep_wc<<<3592, 256, 0, stream>>>(W1, al1, ar1, W2, al2, ar2, wlr, dst, src, cptr, cidx, esrc);
    prep_h<<<MP + 2304, 256, 0, stream>>>(x, Ws, bs, Wc, bc, wl1, wr1,
                                          h0, hbf, el, er, W1, W2, Wt1, Wt2);

    // layer 1
    gemm_bf16<<<dim3(48, 26), 256, 0, stream>>>(hbf, Wt1, feat);
    msg_agg<0><<<MM, 256, 0, stream>>>(feat, cptr, esrc, b1, el, er, hbf, wl2, wr2, el2, er2, nullptr, nullptr);

    // layer 2
    gemm_bf16<<<dim3(48, 26), 256, 0, stream>>>(hbf, Wt2, feat);
    msg_agg<1><<<MM, 256, 0, stream>>>(feat, cptr, esrc, b2, el2, er2, nullptr, nullptr, nullptr, nullptr, nullptr, h0, out);
}